// Round 1
// baseline (2297.703 us; speedup 1.0000x reference)
//
#include <hip/hip_runtime.h>

#define NN 64
#define HIDD 64
#define IN_DIM 34
#define SUN 70
#define NL 3
#define NH 5
#define MAX_E 1024

__device__ __forceinline__ float sigm(float x){ return 1.0f/(1.0f+__expf(-x)); }
__device__ __forceinline__ float ftanh(float x){
  x = fminf(fmaxf(x, -15.0f), 15.0f);
  float e = __expf(2.0f*x);
  return (e-1.0f)/(e+1.0f);
}

// Build CSR (incoming-edge lists per node) + 1/deg into workspace.
__global__ void build_csr(const int* __restrict__ ei, int E,
                          int* __restrict__ adj_off, int* __restrict__ adj_src,
                          float* __restrict__ dinv){
  if (threadIdx.x != 0 || blockIdx.x != 0) return;
  int cnt[NN];
  for (int n=0;n<NN;++n) cnt[n]=0;
  for (int e=0;e<E;++e) cnt[ei[E+e]]++;
  int off=0;
  for (int n=0;n<NN;++n){ adj_off[n]=off; off+=cnt[n]; }
  adj_off[NN]=off;
  int cur[NN];
  for (int n=0;n<NN;++n) cur[n]=0;
  for (int e=0;e<E;++e){ int c=ei[E+e]; adj_src[adj_off[c]+cur[c]++] = ei[e]; }
  for (int n=0;n<NN;++n) dinv[n] = 1.0f/fmaxf((float)cnt[n],1.0f);
}

__global__ __launch_bounds__(256) void gnn_fused(
    const float* __restrict__ nf, const float* __restrict__ sun,
    const int* __restrict__ masks,
    const float* __restrict__ Wp, const float* __restrict__ bp,
    const float* __restrict__ Wself, const float* __restrict__ Wneigh,
    const float* __restrict__ bconv, const float* __restrict__ lng, const float* __restrict__ lnb,
    const float* __restrict__ Wcod, const float* __restrict__ bcod,
    const float* __restrict__ a1W, const float* __restrict__ a1b,
    const float* __restrict__ a2W, const float* __restrict__ a2b,
    const float* __restrict__ oW, const float* __restrict__ ob,
    const float* __restrict__ fW1, const float* __restrict__ fb1,
    const float* __restrict__ fW2, const float* __restrict__ fb2,
    const int* __restrict__ adj_off, const int* __restrict__ adj_src,
    const float* __restrict__ dinv, int E,
    float* __restrict__ out)
{
  __shared__ float s_x[NN*65];      // node states, stride 65 (2-way alias = free)
  __shared__ float s_n[NN*65];      // neighbor aggregate
  __shared__ float s_wA[64*64];     // staged weight A (also nf at stride 35)
  __shared__ float s_wB[64*64];     // staged weight B
  __shared__ float s_red[4*64*2];   // cross-wave row reductions
  __shared__ float s_scal[64];      // softmax weights
  __shared__ float s_pool[4*64];    // pooled partials
  __shared__ float s_scores[8];
  __shared__ float s_dinv[64];
  __shared__ float s_mask[NH*64];
  __shared__ int   s_off[NN+1];
  __shared__ int   s_src[MAX_E];

  const int tid  = threadIdx.x;
  const int lane = tid & 63;
  const int wv   = tid >> 6;
  const long b   = blockIdx.x;

  // ---- stage batch-invariant small data + this element's node features ----
  if (tid < NN+1) s_off[tid] = adj_off[tid];
  for (int e = tid; e < E && e < MAX_E; e += 256) s_src[e] = adj_src[e];
  if (tid < 64) s_dinv[tid] = dinv[tid];
  for (int i = tid; i < NH*64; i += 256) s_mask[i] = (float)masks[i];
  for (int i = tid; i < NN*IN_DIM; i += 256){
    int n = i / IN_DIM, k = i - n*IN_DIM;
    s_wA[n*35+k] = nf[b*(long)(NN*IN_DIM) + i];
  }
  for (int i = tid; i < IN_DIM*HIDD; i += 256) s_wB[i] = Wp[i];
  __syncthreads();

  // ---- input projection: x = relu(nf @ Wp + bp) ----
  {
    float acc[16];
    #pragma unroll
    for (int k=0;k<16;++k) acc[k] = bp[wv*16+k];
    for (int kk=0; kk<IN_DIM; ++kk){
      float a = s_wA[lane*35+kk];
      const float* wr = &s_wB[kk*64 + wv*16];
      #pragma unroll
      for (int k=0;k<16;++k) acc[k] = fmaf(a, wr[k], acc[k]);
    }
    #pragma unroll
    for (int k=0;k<16;++k) s_x[lane*65 + wv*16 + k] = fmaxf(acc[k], 0.0f);
  }
  __syncthreads();

  // ---- GNN layers ----
  for (int L=0; L<NL; ++L){
    for (int i=tid;i<4096;i+=256){ s_wA[i]=Wself[L*4096+i]; s_wB[i]=Wneigh[L*4096+i]; }
    // neighbor mean: 16 rows per wave, one column per lane
    for (int r=0;r<16;++r){
      int n = wv*16 + r;
      float a = 0.0f;
      int p0 = s_off[n], p1 = s_off[n+1];
      for (int p=p0;p<p1;++p) a += s_x[s_src[p]*65 + lane];
      s_n[n*65+lane] = a * s_dinv[n];
    }
    __syncthreads();
    // h = x@Wself + neigh@Wneigh + bconv
    float h[16];
    #pragma unroll
    for (int k=0;k<16;++k) h[k] = bconv[L*64 + wv*16 + k];
    for (int kk=0; kk<64; ++kk){
      float a = s_x[lane*65+kk];
      float c = s_n[lane*65+kk];
      const float* wsr = &s_wA[kk*64 + wv*16];
      const float* wnr = &s_wB[kk*64 + wv*16];
      #pragma unroll
      for (int k=0;k<16;++k) h[k] = fmaf(a, wsr[k], fmaf(c, wnr[k], h[k]));
    }
    // LayerNorm over hid (row = lane, split across 4 waves)
    float sm=0.0f, sq=0.0f;
    #pragma unroll
    for (int k=0;k<16;++k){ sm += h[k]; sq += h[k]*h[k]; }
    s_red[(wv*64+lane)*2+0]=sm; s_red[(wv*64+lane)*2+1]=sq;
    __syncthreads();
    float fs=0.0f, fq=0.0f;
    #pragma unroll
    for (int w=0;w<4;++w){ fs += s_red[(w*64+lane)*2+0]; fq += s_red[(w*64+lane)*2+1]; }
    float mu  = fs*(1.0f/64.0f);
    float var = fq*(1.0f/64.0f) - mu*mu;
    float rs  = rsqrtf(var + 1e-5f);
    #pragma unroll
    for (int k=0;k<16;++k){
      int j = wv*16+k;
      float hn = (h[k]-mu)*rs*lng[L*64+j] + lnb[L*64+j];
      s_x[lane*65+j] += fmaxf(hn, 0.0f);
    }
    __syncthreads();
  }

  // ---- codons: sigmoid(x @ Wcodon + bcodon), one quad of threads per node ----
  {
    int n = tid >> 2, q = tid & 3;
    float p = 0.0f;
    #pragma unroll
    for (int k=0;k<16;++k) p += s_x[n*65 + q*16 + k] * Wcod[q*16+k];
    p += __shfl_xor(p, 1, 64);
    p += __shfl_xor(p, 2, 64);
    if (q==0) out[b*69 + n] = sigm(p + bcod[0]);
  }

  // ---- awareness heads ----
  for (int hd=0; hd<NH; ++hd){
    __syncthreads();
    for (int i=tid;i<2048;i+=256) s_wA[i] = a1W[hd*2048+i];
    __syncthreads();
    // t1 = tanh(m*(x@W1) + b1); per-thread partial of t1 @ W2
    float acc[8];
    #pragma unroll
    for (int k=0;k<8;++k) acc[k]=0.0f;
    for (int kk=0;kk<64;++kk){
      float a = s_x[lane*65+kk];
      const float* wr = &s_wA[kk*32 + wv*8];
      #pragma unroll
      for (int k=0;k<8;++k) acc[k] = fmaf(a, wr[k], acc[k]);
    }
    float m = s_mask[hd*64 + lane];
    float sp = 0.0f;
    #pragma unroll
    for (int k=0;k<8;++k){
      float t = ftanh(m*acc[k] + a1b[hd*32 + wv*8 + k]);
      sp += t * a2W[hd*32 + wv*8 + k];
    }
    s_red[(wv*64+lane)*2] = sp;
    __syncthreads();
    float sv = a2b[hd] + (1.0f - m)*(-1.0e9f);
    #pragma unroll
    for (int w=0;w<4;++w) sv += s_red[(w*64+lane)*2];
    // softmax over the 64 nodes (per-wave redundant, shuffle tree)
    float mx = sv;
    #pragma unroll
    for (int d=32; d>=1; d>>=1) mx = fmaxf(mx, __shfl_xor(mx, d, 64));
    float e = __expf(sv - mx);
    float ssum = e;
    #pragma unroll
    for (int d=32; d>=1; d>>=1) ssum += __shfl_xor(ssum, d, 64);
    float wgt = (e / ssum) * m;   // fold mask into weight: pooled = sum w*m*x
    if (wv==0) s_scal[lane] = wgt;
    __syncthreads();
    // pooled[j]: 16 nodes per wave
    float pp = 0.0f;
    for (int r=0;r<16;++r){
      int n = wv*16+r;
      pp = fmaf(s_scal[n], s_x[n*65+lane], pp);
    }
    s_pool[wv*64+lane] = pp;
    __syncthreads();
    float ps = 0.0f;
    #pragma unroll
    for (int w=0;w<4;++w) ps += s_pool[w*64+lane];
    float c = ps * oW[hd*64 + lane];
    #pragma unroll
    for (int d=32; d>=1; d>>=1) c += __shfl_xor(c, d, 64);
    if (tid==0) s_scores[hd] = sigm(c + ob[hd]);
  }
  __syncthreads();

  // ---- FiLM (waves 0/1, lanes 0..31) + scalar outputs ----
  if (wv < 2 && lane < 32){
    int idx = wv;
    float t = fb1[idx*32 + lane];
    for (int k=0;k<SUN;++k) t = fmaf(sun[b*(long)SUN + k], fW1[idx*SUN*32 + k*32 + lane], t);
    t = fmaxf(t, 0.0f);
    float g  = t * fW2[idx*64 + lane*2 + 0];
    float be = t * fW2[idx*64 + lane*2 + 1];
    #pragma unroll
    for (int d=16; d>=1; d>>=1){ g += __shfl_xor(g, d, 64); be += __shfl_xor(be, d, 64); }
    if (lane==0){
      g  += fb2[idx*2 + 0];
      be += fb2[idx*2 + 1];
      float base = s_scores[3+idx];
      out[b*69 + 67 + idx] = sigm(fmaf(g, base, be));
    }
  }
  if (tid < 3) out[b*69 + 64 + tid] = s_scores[tid];
}

extern "C" void kernel_launch(void* const* d_in, const int* in_sizes, int n_in,
                              void* d_out, int out_size, void* d_ws, size_t ws_size,
                              hipStream_t stream){
  const float* nf     = (const float*)d_in[0];
  const float* sun    = (const float*)d_in[1];
  const int*   ei     = (const int*)d_in[2];
  const int*   masks  = (const int*)d_in[3];
  const float* Wp     = (const float*)d_in[4];
  const float* bp     = (const float*)d_in[5];
  const float* Wself  = (const float*)d_in[6];
  const float* Wneigh = (const float*)d_in[7];
  const float* bconv  = (const float*)d_in[8];
  const float* lng    = (const float*)d_in[9];
  const float* lnb    = (const float*)d_in[10];
  const float* Wcod   = (const float*)d_in[11];
  const float* bcod   = (const float*)d_in[12];
  const float* a1W    = (const float*)d_in[13];
  const float* a1b    = (const float*)d_in[14];
  const float* a2W    = (const float*)d_in[15];
  const float* a2b    = (const float*)d_in[16];
  const float* oW     = (const float*)d_in[17];
  const float* ob     = (const float*)d_in[18];
  const float* fW1    = (const float*)d_in[19];
  const float* fb1    = (const float*)d_in[20];
  const float* fW2    = (const float*)d_in[21];
  const float* fb2    = (const float*)d_in[22];

  int B = in_sizes[0] / (NN*IN_DIM);
  int E = in_sizes[2] / 2;

  int* adj_off = (int*)d_ws;
  int* adj_src = adj_off + (NN+1);
  float* dinv  = (float*)(adj_src + MAX_E);

  build_csr<<<1, 64, 0, stream>>>(ei, E, adj_off, adj_src, dinv);
  gnn_fused<<<B, 256, 0, stream>>>(nf, sun, masks, Wp, bp, Wself, Wneigh, bconv,
      lng, lnb, Wcod, bcod, a1W, a1b, a2W, a2b, oW, ob, fW1, fb1, fW2, fb2,
      adj_off, adj_src, dinv, E, (float*)d_out);
}

// Round 2
// 1540.428 us; speedup vs baseline: 1.4916x; 1.4916x over previous
//
#include <hip/hip_runtime.h>

#define NN 64
#define HIDD 64
#define IN_DIM 34
#define SUN 70
#define NL 3
#define NH 5
#define MAX_E 512

__device__ __forceinline__ float sigm(float x){ return 1.0f/(1.0f+__expf(-x)); }
__device__ __forceinline__ float ftanh(float x){
  x = fminf(fmaxf(x, -15.0f), 15.0f);
  float e = __expf(2.0f*x);
  return (e-1.0f)/(e+1.0f);
}

// Build CSR (incoming-edge lists per node) + 1/deg into workspace.
__global__ void build_csr(const int* __restrict__ ei, int E,
                          int* __restrict__ adj_off, int* __restrict__ adj_src,
                          float* __restrict__ dinv){
  if (threadIdx.x != 0 || blockIdx.x != 0) return;
  int cnt[NN];
  for (int n=0;n<NN;++n) cnt[n]=0;
  for (int e=0;e<E;++e) cnt[ei[E+e]]++;
  int off=0;
  for (int n=0;n<NN;++n){ adj_off[n]=off; off+=cnt[n]; }
  adj_off[NN]=off;
  int cur[NN];
  for (int n=0;n<NN;++n) cur[n]=0;
  for (int e=0;e<E;++e){ int c=ei[E+e]; adj_src[adj_off[c]+cur[c]++] = ei[e]; }
  for (int n=0;n<NN;++n) dinv[n] = 1.0f/fmaxf((float)cnt[n],1.0f);
}

__global__ __launch_bounds__(256, 4) void gnn_fused(
    const float* __restrict__ nf, const float* __restrict__ sun,
    const int* __restrict__ masks,
    const float* __restrict__ Wp, const float* __restrict__ bp,
    const float* __restrict__ Wself, const float* __restrict__ Wneigh,
    const float* __restrict__ bconv, const float* __restrict__ lng, const float* __restrict__ lnb,
    const float* __restrict__ Wcod, const float* __restrict__ bcod,
    const float* __restrict__ a1W, const float* __restrict__ a1b,
    const float* __restrict__ a2W, const float* __restrict__ a2b,
    const float* __restrict__ oW, const float* __restrict__ ob,
    const float* __restrict__ fW1, const float* __restrict__ fb1,
    const float* __restrict__ fW2, const float* __restrict__ fb2,
    const int* __restrict__ adj_off, const int* __restrict__ adj_src,
    const float* __restrict__ dinv, int E,
    float* __restrict__ out)
{
  __shared__ float s_x[NN*65];      // node states, stride 65 (2-way alias = free)
  __shared__ float s_n[NN*65];      // nf staging -> neighbor agg -> head scratch
  __shared__ float s_red[4*64*2];   // cross-wave LN reductions
  __shared__ float s_scores[8];
  __shared__ float s_dinv[64];
  __shared__ float s_mask[NH*64];
  __shared__ int   s_off[NN+1];
  __shared__ int   s_src[MAX_E];

  float* s_redh  = s_n;             // [NH][4][64]  (heads phase, s_n dead)
  float* s_poolh = s_n + NH*256;    // [NH][4][64]

  const int tid  = threadIdx.x;
  const int lane = tid & 63;
  const int wv   = tid >> 6;
  const int wvu  = __builtin_amdgcn_readfirstlane(wv);   // provably wave-uniform
  const long b   = blockIdx.x;

  // ---- stage batch-invariant small data + this element's node features ----
  if (tid < NN+1) s_off[tid] = adj_off[tid];
  for (int e = tid; e < E && e < MAX_E; e += 256) s_src[e] = adj_src[e];
  if (tid < 64) s_dinv[tid] = dinv[tid];
  for (int i = tid; i < NH*64; i += 256) s_mask[i] = (float)masks[i];
  for (int i = tid; i < NN*IN_DIM; i += 256){
    int n = i / IN_DIM, k = i - n*IN_DIM;
    s_n[n*65+k] = nf[b*(long)(NN*IN_DIM) + i];
  }
  __syncthreads();

  // ---- input projection: x = relu(nf @ Wp + bp) ----
  {
    float acc[16];
    #pragma unroll
    for (int k=0;k<16;++k) acc[k] = bp[wvu*16+k];
    #pragma unroll 2
    for (int kk=0; kk<IN_DIM; ++kk){
      float a = s_n[lane*65+kk];
      const float* wr = &Wp[kk*64 + wvu*16];
      #pragma unroll
      for (int k=0;k<16;++k) acc[k] = fmaf(a, wr[k], acc[k]);
    }
    #pragma unroll
    for (int k=0;k<16;++k) s_x[lane*65 + wvu*16 + k] = fmaxf(acc[k], 0.0f);
  }
  __syncthreads();

  // ---- GNN layers ----
  for (int L=0; L<NL; ++L){
    // neighbor mean: 16 rows per wave, one column per lane
    for (int r=0;r<16;++r){
      int n = wvu*16 + r;
      float a = 0.0f;
      int p0 = s_off[n], p1 = s_off[n+1];
      for (int p=p0;p<p1;++p) a += s_x[s_src[p]*65 + lane];
      s_n[n*65+lane] = a * s_dinv[n];
    }
    __syncthreads();
    // h = x@Wself + neigh@Wneigh + bconv   (weights: wave-uniform s_loads)
    float h[16];
    #pragma unroll
    for (int k=0;k<16;++k) h[k] = bconv[L*64 + wvu*16 + k];
    const float* Ws = Wself  + L*4096 + wvu*16;
    const float* Wn = Wneigh + L*4096 + wvu*16;
    #pragma unroll 4
    for (int kk=0; kk<64; ++kk){
      float a = s_x[lane*65+kk];
      float c = s_n[lane*65+kk];
      #pragma unroll
      for (int k=0;k<16;++k) h[k] = fmaf(a, Ws[kk*64+k], fmaf(c, Wn[kk*64+k], h[k]));
    }
    // LayerNorm over hid (row = lane, split across 4 waves)
    float sm=0.0f, sq=0.0f;
    #pragma unroll
    for (int k=0;k<16;++k){ sm += h[k]; sq += h[k]*h[k]; }
    s_red[(wvu*64+lane)*2+0]=sm; s_red[(wvu*64+lane)*2+1]=sq;
    __syncthreads();
    float fs=0.0f, fq=0.0f;
    #pragma unroll
    for (int w=0;w<4;++w){ fs += s_red[(w*64+lane)*2+0]; fq += s_red[(w*64+lane)*2+1]; }
    float mu  = fs*(1.0f/64.0f);
    float var = fq*(1.0f/64.0f) - mu*mu;
    float rs  = rsqrtf(var + 1e-5f);
    #pragma unroll
    for (int k=0;k<16;++k){
      int j = wvu*16+k;
      float hn = (h[k]-mu)*rs*lng[L*64+j] + lnb[L*64+j];
      s_x[lane*65+j] += fmaxf(hn, 0.0f);
    }
    __syncthreads();
  }

  // ---- codons: sigmoid(x @ Wcodon + bcodon), one quad of threads per node ----
  {
    int n = tid >> 2, q = tid & 3;
    float p = 0.0f;
    #pragma unroll
    for (int k=0;k<16;++k) p += s_x[n*65 + q*16 + k] * Wcod[q*16+k];
    p += __shfl_xor(p, 1, 64);
    p += __shfl_xor(p, 2, 64);
    if (q==0) out[b*69 + n] = sigm(p + bcod[0]);
  }

  // ---- awareness heads: fused phase 1 (all heads' attn-score partials) ----
  {
    float acc[NH][8];
    #pragma unroll
    for (int hd=0; hd<NH; ++hd)
      #pragma unroll
      for (int k=0;k<8;++k) acc[hd][k]=0.0f;
    #pragma unroll 2
    for (int kk=0;kk<64;++kk){
      float a = s_x[lane*65+kk];
      #pragma unroll
      for (int hd=0; hd<NH; ++hd){
        const float* wr = &a1W[hd*2048 + kk*32 + wvu*8];
        #pragma unroll
        for (int k=0;k<8;++k) acc[hd][k] = fmaf(a, wr[k], acc[hd][k]);
      }
    }
    #pragma unroll
    for (int hd=0; hd<NH; ++hd){
      float m = s_mask[hd*64 + lane];
      float sp = 0.0f;
      #pragma unroll
      for (int k=0;k<8;++k){
        float t = ftanh(m*acc[hd][k] + a1b[hd*32 + wvu*8 + k]);
        sp += t * a2W[hd*32 + wvu*8 + k];
      }
      s_redh[hd*256 + wvu*64 + lane] = sp;
    }
  }
  __syncthreads();

  // ---- phase 2: softmax (per-wave redundant) + pooled partials ----
  #pragma unroll
  for (int hd=0; hd<NH; ++hd){
    float m = s_mask[hd*64 + lane];
    float sv = a2b[hd] + (1.0f - m)*(-1.0e9f);
    #pragma unroll
    for (int w=0;w<4;++w) sv += s_redh[hd*256 + w*64 + lane];
    float mx = sv;
    #pragma unroll
    for (int d=32; d>=1; d>>=1) mx = fmaxf(mx, __shfl_xor(mx, d, 64));
    float e = __expf(sv - mx);
    float ssum = e;
    #pragma unroll
    for (int d=32; d>=1; d>>=1) ssum += __shfl_xor(ssum, d, 64);
    float wgt = (e / ssum) * m;   // mask folded into weight
    float pp = 0.0f;
    #pragma unroll
    for (int r=0;r<16;++r){
      int n = wvu*16+r;
      pp = fmaf(__shfl(wgt, n, 64), s_x[n*65+lane], pp);
    }
    s_poolh[hd*256 + wvu*64 + lane] = pp;
  }
  __syncthreads();

  // ---- phase 3: output dots (wave 0 only) ----
  if (wvu == 0){
    #pragma unroll
    for (int hd=0; hd<NH; ++hd){
      float ps = 0.0f;
      #pragma unroll
      for (int w=0;w<4;++w) ps += s_poolh[hd*256 + w*64 + lane];
      float c = ps * oW[hd*64 + lane];
      #pragma unroll
      for (int d=32; d>=1; d>>=1) c += __shfl_xor(c, d, 64);
      if (lane==0) s_scores[hd] = sigm(c + ob[hd]);
    }
  }
  __syncthreads();

  // ---- FiLM (waves 0/1, lanes 0..31) + scalar outputs ----
  if (wvu < 2 && lane < 32){
    int idx = wvu;
    float t = fb1[idx*32 + lane];
    for (int k=0;k<SUN;++k) t = fmaf(sun[b*(long)SUN + k], fW1[idx*SUN*32 + k*32 + lane], t);
    t = fmaxf(t, 0.0f);
    float g  = t * fW2[idx*64 + lane*2 + 0];
    float be = t * fW2[idx*64 + lane*2 + 1];
    #pragma unroll
    for (int d=16; d>=1; d>>=1){ g += __shfl_xor(g, d, 64); be += __shfl_xor(be, d, 64); }
    if (lane==0){
      g  += fb2[idx*2 + 0];
      be += fb2[idx*2 + 1];
      float base = s_scores[3+idx];
      out[b*69 + 67 + idx] = sigm(fmaf(g, base, be));
    }
  }
  if (tid < 3) out[b*69 + 64 + tid] = s_scores[tid];
}

extern "C" void kernel_launch(void* const* d_in, const int* in_sizes, int n_in,
                              void* d_out, int out_size, void* d_ws, size_t ws_size,
                              hipStream_t stream){
  const float* nf     = (const float*)d_in[0];
  const float* sun    = (const float*)d_in[1];
  const int*   ei     = (const int*)d_in[2];
  const int*   masks  = (const int*)d_in[3];
  const float* Wp     = (const float*)d_in[4];
  const float* bp     = (const float*)d_in[5];
  const float* Wself  = (const float*)d_in[6];
  const float* Wneigh = (const float*)d_in[7];
  const float* bconv  = (const float*)d_in[8];
  const float* lng    = (const float*)d_in[9];
  const float* lnb    = (const float*)d_in[10];
  const float* Wcod   = (const float*)d_in[11];
  const float* bcod   = (const float*)d_in[12];
  const float* a1W    = (const float*)d_in[13];
  const float* a1b    = (const float*)d_in[14];
  const float* a2W    = (const float*)d_in[15];
  const float* a2b    = (const float*)d_in[16];
  const float* oW     = (const float*)d_in[17];
  const float* ob     = (const float*)d_in[18];
  const float* fW1    = (const float*)d_in[19];
  const float* fb1    = (const float*)d_in[20];
  const float* fW2    = (const float*)d_in[21];
  const float* fb2    = (const float*)d_in[22];

  int B = in_sizes[0] / (NN*IN_DIM);
  int E = in_sizes[2] / 2;

  int* adj_off = (int*)d_ws;
  int* adj_src = adj_off + (NN+1);
  float* dinv  = (float*)(adj_src + MAX_E);

  build_csr<<<1, 64, 0, stream>>>(ei, E, adj_off, adj_src, dinv);
  gnn_fused<<<B, 256, 0, stream>>>(nf, sun, masks, Wp, bp, Wself, Wneigh, bconv,
      lng, lnb, Wcod, bcod, a1W, a1b, a2W, a2b, oW, ob, fW1, fb1, fW2, fb2,
      adj_off, adj_src, dinv, E, (float*)d_out);
}

// Round 4
// 1355.827 us; speedup vs baseline: 1.6947x; 1.1362x over previous
//
#include <hip/hip_runtime.h>

#define NN 64
#define HIDD 64
#define IN_DIM 34
#define SUN 70
#define NL 3
#define NH 5
#define MAX_E 512

typedef __attribute__((ext_vector_type(8))) short short8;
typedef __attribute__((ext_vector_type(4))) float f32x4;
#define MFMA16 __builtin_amdgcn_mfma_f32_16x16x32_bf16

__device__ __forceinline__ float sigm(float x){ return 1.0f/(1.0f+__expf(-x)); }
__device__ __forceinline__ float ftanh(float x){
  x = fminf(fmaxf(x, -15.0f), 15.0f);
  float e = __expf(2.0f*x);
  return (e-1.0f)/(e+1.0f);
}
__device__ __forceinline__ ushort f2bf(float f){
  union { float f; unsigned u; } v; v.f = f;
  unsigned r = v.u + 0x7fff + ((v.u >> 16) & 1);   // RNE
  return (ushort)(r >> 16);
}
__device__ __forceinline__ float bf2f(ushort h){
  union { unsigned u; float f; } v; v.u = ((unsigned)h) << 16;
  return v.f;
}

// swizzled LDS offset within a [64][64] ushort plane (T2-style, 16B groups)
__device__ __forceinline__ int SWZ(int row, int col){
  return row*64 + (col ^ ((row&7)<<3));
}

// ws ushort offsets (after 2576B of CSR data)
#define O_WPH 0
#define O_WPL 4096
#define O_WSH 8192
#define O_WSL 20480
#define O_WNH 32768
#define O_WNL 45056
#define O_A1H 57344
#define O_A1L 67584

// Setup: CSR (thread 0) + weight bf16 hi/lo transpose conversion.
__global__ void setup_k(const int* __restrict__ ei, int E,
                        const float* __restrict__ Wp, const float* __restrict__ Wself,
                        const float* __restrict__ Wneigh, const float* __restrict__ a1W,
                        int* __restrict__ adj_off, int* __restrict__ adj_src,
                        float* __restrict__ dinv, ushort* __restrict__ wb){
  int tid = threadIdx.x;
  if (tid == 0){
    int cnt[NN];
    for (int n=0;n<NN;++n) cnt[n]=0;
    for (int e=0;e<E;++e) cnt[ei[E+e]]++;
    int off=0;
    for (int n=0;n<NN;++n){ adj_off[n]=off; off+=cnt[n]; }
    adj_off[NN]=off;
    int cur[NN];
    for (int n=0;n<NN;++n) cur[n]=0;
    for (int e=0;e<E;++e){ int c=ei[E+e]; adj_src[adj_off[c]+cur[c]++] = ei[e]; }
    for (int n=0;n<NN;++n) dinv[n] = 1.0f/fmaxf((float)cnt[n],1.0f);
  }
  // WpT hi/lo: [n][k], k>=IN_DIM zero
  for (int i = tid; i < 4096; i += 256){
    int n = i>>6, k = i&63;
    float w = (k < IN_DIM) ? Wp[k*64 + n] : 0.0f;
    ushort h = f2bf(w);
    wb[O_WPH+i] = h;
    wb[O_WPL+i] = f2bf(w - bf2f(h));
  }
  // WsT/WnT hi/lo: [L][n][k]
  for (int i = tid; i < 3*4096; i += 256){
    int L = i>>12, r = i&4095, n = r>>6, k = r&63;
    float w = Wself[L*4096 + k*64 + n];
    ushort h = f2bf(w);
    wb[O_WSH+i] = h; wb[O_WSL+i] = f2bf(w - bf2f(h));
    w = Wneigh[L*4096 + k*64 + n];
    h = f2bf(w);
    wb[O_WNH+i] = h; wb[O_WNL+i] = f2bf(w - bf2f(h));
  }
  // A1T hi/lo: [hd][c][k]
  for (int i = tid; i < 5*2048; i += 256){
    int hd = i>>11, r = i&2047, cc = r>>6, k = r&63;
    float w = a1W[hd*2048 + k*32 + cc];
    ushort h = f2bf(w);
    wb[O_A1H+i] = h; wb[O_A1L+i] = f2bf(w - bf2f(h));
  }
}

__global__ __launch_bounds__(256, 4) void gnn_fused(
    const float* __restrict__ nf, const float* __restrict__ sun,
    const int* __restrict__ masks,
    const float* __restrict__ bp, const float* __restrict__ bconv,
    const float* __restrict__ lng, const float* __restrict__ lnb,
    const float* __restrict__ Wcod, const float* __restrict__ bcod,
    const float* __restrict__ a1b, const float* __restrict__ a2W,
    const float* __restrict__ a2b,
    const float* __restrict__ oW, const float* __restrict__ ob,
    const float* __restrict__ fW1, const float* __restrict__ fb1,
    const float* __restrict__ fW2, const float* __restrict__ fb2,
    const int* __restrict__ adj_off, const int* __restrict__ adj_src,
    const float* __restrict__ dinv, const ushort* __restrict__ wb, int E,
    float* __restrict__ out)
{
  __shared__ ushort s_xb[2*4096];  // x bf16 hi(plane0)/lo(plane1), swizzled
  __shared__ ushort s_nb[2*4096];  // nf/neigh hi/lo -> heads scratch
  __shared__ float  s_scores[8];
  __shared__ float  s_dinv[64];
  __shared__ float  s_mask[NH*64];
  __shared__ int    s_off[NN+1];
  __shared__ int    s_src[MAX_E];

  float* s_scH  = (float*)s_nb;          // [5][64]
  float* s_pool = s_scH + NH*64;         // [5][4][64]

  const int tid  = threadIdx.x;
  const int lane = tid & 63;
  const int wv   = __builtin_amdgcn_readfirstlane(tid >> 6);
  const int c    = lane & 15;            // tile col (A-row / D-col index)
  const int hk   = lane >> 4;            // K-group (0..3)
  const long b   = blockIdx.x;

  // ---- stage ----
  if (tid < NN+1) s_off[tid] = adj_off[tid];
  for (int e = tid; e < E && e < MAX_E; e += 256) s_src[e] = adj_src[e];
  if (tid < 64) s_dinv[tid] = dinv[tid];
  for (int i = tid; i < NH*64; i += 256) s_mask[i] = (float)masks[i];
  for (int i = tid; i < NN*IN_DIM; i += 256){
    int n = i / IN_DIM, k = i - n*IN_DIM;
    float v = nf[b*(long)(NN*IN_DIM) + i];
    ushort h = f2bf(v);
    int o = SWZ(n,k);
    s_nb[o] = h; s_nb[4096+o] = f2bf(v - bf2f(h));
  }
  for (int i = tid; i < NN*(64-IN_DIM); i += 256){
    int n = i / (64-IN_DIM), k = IN_DIM + (i - n*(64-IN_DIM));
    int o = SWZ(n,k);
    s_nb[o] = 0; s_nb[4096+o] = 0;
  }
  __syncthreads();

  float xr[4][4];   // x in C-frag layout: [nt][r], col=16nt+c, row=16wv+hk*4+r
  const int arow = 16*wv + c;

  // ---- proj: x = relu(nf @ Wp + bp), MFMA hi/lo ----
  {
    f32x4 acc[4];
    #pragma unroll
    for (int nt=0;nt<4;++nt){
      float bias = bp[16*nt + c];
      acc[nt] = (f32x4){bias,bias,bias,bias};
    }
    #pragma unroll
    for (int ks=0; ks<2; ++ks){
      int ao = SWZ(arow, hk*8 + ks*32);
      short8 aH = *(const short8*)&s_nb[ao];
      short8 aL = *(const short8*)&s_nb[4096+ao];
      #pragma unroll
      for (int nt=0;nt<4;++nt){
        int boff = (16*nt+c)*64 + hk*8 + ks*32;
        acc[nt] = MFMA16(aH, *(const short8*)(wb+O_WPH+boff), acc[nt], 0,0,0);
        acc[nt] = MFMA16(aH, *(const short8*)(wb+O_WPL+boff), acc[nt], 0,0,0);
        acc[nt] = MFMA16(aL, *(const short8*)(wb+O_WPH+boff), acc[nt], 0,0,0);
      }
    }
    #pragma unroll
    for (int nt=0;nt<4;++nt)
      #pragma unroll
      for (int r=0;r<4;++r){
        float v = fmaxf(acc[nt][r], 0.0f);
        xr[nt][r] = v;
        int row = 16*wv + hk*4 + r;
        int o = SWZ(row, 16*nt+c);
        ushort h = f2bf(v);
        s_xb[o] = h; s_xb[4096+o] = f2bf(v - bf2f(h));
      }
  }
  __syncthreads();

  // ---- GNN layers ----
  for (int L=0; L<NL; ++L){
    // gather (reads all of s_xb hi+lo, writes own rows of s_nb)
    for (int r16=0; r16<16; ++r16){
      int n = wv*16 + r16;
      float a = 0.0f;
      int p0 = s_off[n], p1 = s_off[n+1];
      for (int p=p0;p<p1;++p){
        int o = SWZ(s_src[p], lane);
        a += bf2f(s_xb[o]) + bf2f(s_xb[4096+o]);
      }
      float v = a * s_dinv[n];
      ushort h = f2bf(v);
      int o = SWZ(n, lane);
      s_nb[o] = h; s_nb[4096+o] = f2bf(v - bf2f(h));
    }
    // A-fragments (own rows), hi/lo
    int a0 = SWZ(arow, hk*8), a1 = SWZ(arow, hk*8+32);
    short8 xA0H = *(const short8*)&s_xb[a0];
    short8 xA0L = *(const short8*)&s_xb[4096+a0];
    short8 xA1H = *(const short8*)&s_xb[a1];
    short8 xA1L = *(const short8*)&s_xb[4096+a1];
    short8 nA0H = *(const short8*)&s_nb[a0];
    short8 nA0L = *(const short8*)&s_nb[4096+a0];
    short8 nA1H = *(const short8*)&s_nb[a1];
    short8 nA1L = *(const short8*)&s_nb[4096+a1];

    f32x4 acc[4];
    #pragma unroll
    for (int nt=0;nt<4;++nt){
      float bias = bconv[L*64 + 16*nt + c];
      acc[nt] = (f32x4){bias,bias,bias,bias};
    }
    const ushort* WsH = wb + O_WSH + L*4096;
    const ushort* WsL = wb + O_WSL + L*4096;
    const ushort* WnH = wb + O_WNH + L*4096;
    const ushort* WnL = wb + O_WNL + L*4096;
    #pragma unroll
    for (int nt=0;nt<4;++nt){
      int boff = (16*nt+c)*64 + hk*8;
      acc[nt] = MFMA16(xA0H, *(const short8*)(WsH+boff   ), acc[nt], 0,0,0);
      acc[nt] = MFMA16(xA0H, *(const short8*)(WsL+boff   ), acc[nt], 0,0,0);
      acc[nt] = MFMA16(xA0L, *(const short8*)(WsH+boff   ), acc[nt], 0,0,0);
      acc[nt] = MFMA16(nA0H, *(const short8*)(WnH+boff   ), acc[nt], 0,0,0);
      acc[nt] = MFMA16(nA0H, *(const short8*)(WnL+boff   ), acc[nt], 0,0,0);
      acc[nt] = MFMA16(nA0L, *(const short8*)(WnH+boff   ), acc[nt], 0,0,0);
      acc[nt] = MFMA16(xA1H, *(const short8*)(WsH+boff+32), acc[nt], 0,0,0);
      acc[nt] = MFMA16(xA1H, *(const short8*)(WsL+boff+32), acc[nt], 0,0,0);
      acc[nt] = MFMA16(xA1L, *(const short8*)(WsH+boff+32), acc[nt], 0,0,0);
      acc[nt] = MFMA16(nA1H, *(const short8*)(WnH+boff+32), acc[nt], 0,0,0);
      acc[nt] = MFMA16(nA1H, *(const short8*)(WnL+boff+32), acc[nt], 0,0,0);
      acc[nt] = MFMA16(nA1L, *(const short8*)(WnH+boff+32), acc[nt], 0,0,0);
    }
    __syncthreads();   // all s_xb/s_nb reads done before x rewrite

    // LN + relu + residual, in-register
    float g4[4], b4[4];
    #pragma unroll
    for (int nt=0;nt<4;++nt){ g4[nt]=lng[L*64+16*nt+c]; b4[nt]=lnb[L*64+16*nt+c]; }
    #pragma unroll
    for (int r=0;r<4;++r){
      float sm = acc[0][r]+acc[1][r]+acc[2][r]+acc[3][r];
      float sq = acc[0][r]*acc[0][r]+acc[1][r]*acc[1][r]+acc[2][r]*acc[2][r]+acc[3][r]*acc[3][r];
      #pragma unroll
      for (int d=1; d<16; d<<=1){ sm += __shfl_xor(sm, d, 64); sq += __shfl_xor(sq, d, 64); }
      float mu  = sm*(1.0f/64.0f);
      float var = sq*(1.0f/64.0f) - mu*mu;
      float rs  = rsqrtf(var + 1e-5f);
      int row = 16*wv + hk*4 + r;
      #pragma unroll
      for (int nt=0;nt<4;++nt){
        float hn = (acc[nt][r]-mu)*rs*g4[nt] + b4[nt];
        float v  = xr[nt][r] + fmaxf(hn, 0.0f);
        xr[nt][r] = v;
        int o = SWZ(row, 16*nt+c);
        ushort h = f2bf(v);
        s_xb[o] = h; s_xb[4096+o] = f2bf(v - bf2f(h));
      }
    }
    __syncthreads();
  }

  // ---- codons from registers ----
  {
    float wc[4];
    #pragma unroll
    for (int nt=0;nt<4;++nt) wc[nt] = Wcod[16*nt+c];
    #pragma unroll
    for (int r=0;r<4;++r){
      float p = xr[0][r]*wc[0] + xr[1][r]*wc[1] + xr[2][r]*wc[2] + xr[3][r]*wc[3];
      #pragma unroll
      for (int d=1; d<16; d<<=1) p += __shfl_xor(p, d, 64);
      if (c == 0){
        int row = 16*wv + hk*4 + r;
        out[b*69 + row] = sigm(p + bcod[0]);
      }
    }
  }

  // ---- heads phase 1: scores via MFMA (bias after mask-mul; writes s_scH) ----
  {
    int a0 = SWZ(arow, hk*8), a1 = SWZ(arow, hk*8+32);
    short8 xA0H = *(const short8*)&s_xb[a0];
    short8 xA0L = *(const short8*)&s_xb[4096+a0];
    short8 xA1H = *(const short8*)&s_xb[a1];
    short8 xA1L = *(const short8*)&s_xb[4096+a1];
    for (int hd=0; hd<NH; ++hd){
      f32x4 acc2[2];
      acc2[0] = (f32x4){0.f,0.f,0.f,0.f};
      acc2[1] = (f32x4){0.f,0.f,0.f,0.f};
      #pragma unroll
      for (int nt=0;nt<2;++nt){
        int boff = hd*2048 + (16*nt+c)*64 + hk*8;
        acc2[nt] = MFMA16(xA0H, *(const short8*)(wb+O_A1H+boff   ), acc2[nt], 0,0,0);
        acc2[nt] = MFMA16(xA0H, *(const short8*)(wb+O_A1L+boff   ), acc2[nt], 0,0,0);
        acc2[nt] = MFMA16(xA0L, *(const short8*)(wb+O_A1H+boff   ), acc2[nt], 0,0,0);
        acc2[nt] = MFMA16(xA1H, *(const short8*)(wb+O_A1H+boff+32), acc2[nt], 0,0,0);
        acc2[nt] = MFMA16(xA1H, *(const short8*)(wb+O_A1L+boff+32), acc2[nt], 0,0,0);
        acc2[nt] = MFMA16(xA1L, *(const short8*)(wb+O_A1H+boff+32), acc2[nt], 0,0,0);
      }
      float b1v0 = a1b[hd*32 +      c];
      float b1v1 = a1b[hd*32 + 16 + c];
      float a2v0 = a2W[hd*32 +      c];
      float a2v1 = a2W[hd*32 + 16 + c];
      #pragma unroll
      for (int r=0;r<4;++r){
        int row = 16*wv + hk*4 + r;
        float m = s_mask[hd*64 + row];
        float sp = ftanh(fmaf(m, acc2[0][r], b1v0)) * a2v0
                 + ftanh(fmaf(m, acc2[1][r], b1v1)) * a2v1;
        #pragma unroll
        for (int d=1; d<16; d<<=1) sp += __shfl_xor(sp, d, 64);
        if (c==0) s_scH[hd*64 + row] = sp + a2b[hd] + (1.0f - m)*(-1.0e9f);
      }
    }
  }
  __syncthreads();

  // ---- phase 2: softmax + pooled partials ----
  #pragma unroll
  for (int hd=0; hd<NH; ++hd){
    float m  = s_mask[hd*64 + lane];
    float sv = s_scH[hd*64 + lane];
    float mx = sv;
    #pragma unroll
    for (int d=32; d>=1; d>>=1) mx = fmaxf(mx, __shfl_xor(mx, d, 64));
    float e = __expf(sv - mx);
    float ssum = e;
    #pragma unroll
    for (int d=32; d>=1; d>>=1) ssum += __shfl_xor(ssum, d, 64);
    float wgt = (e / ssum) * m;
    float pp = 0.0f;
    #pragma unroll
    for (int r16=0; r16<16; ++r16){
      int n = wv*16 + r16;
      int o = SWZ(n, lane);
      float xv = bf2f(s_xb[o]) + bf2f(s_xb[4096+o]);
      pp = fmaf(__shfl(wgt, n, 64), xv, pp);
    }
    s_pool[hd*256 + wv*64 + lane] = pp;
  }
  __syncthreads();

  // ---- phase 3: output dots (wave 0) ----
  if (wv == 0){
    #pragma unroll
    for (int hd=0; hd<NH; ++hd){
      float ps = 0.0f;
      #pragma unroll
      for (int w=0;w<4;++w) ps += s_pool[hd*256 + w*64 + lane];
      float cc = ps * oW[hd*64 + lane];
      #pragma unroll
      for (int d=32; d>=1; d>>=1) cc += __shfl_xor(cc, d, 64);
      if (lane==0) s_scores[hd] = sigm(cc + ob[hd]);
    }
  }
  __syncthreads();

  // ---- FiLM + scalar outputs ----
  if (wv < 2 && lane < 32){
    int idx = wv;
    float t = fb1[idx*32 + lane];
    for (int k=0;k<SUN;++k) t = fmaf(sun[b*(long)SUN + k], fW1[idx*SUN*32 + k*32 + lane], t);
    t = fmaxf(t, 0.0f);
    float g  = t * fW2[idx*64 + lane*2 + 0];
    float be = t * fW2[idx*64 + lane*2 + 1];
    #pragma unroll
    for (int d=16; d>=1; d>>=1){ g += __shfl_xor(g, d, 64); be += __shfl_xor(be, d, 64); }
    if (lane==0){
      g  += fb2[idx*2 + 0];
      be += fb2[idx*2 + 1];
      float base = s_scores[3+idx];
      out[b*69 + 67 + idx] = sigm(fmaf(g, base, be));
    }
  }
  if (tid < 3) out[b*69 + 64 + tid] = s_scores[tid];
}

extern "C" void kernel_launch(void* const* d_in, const int* in_sizes, int n_in,
                              void* d_out, int out_size, void* d_ws, size_t ws_size,
                              hipStream_t stream){
  const float* nf     = (const float*)d_in[0];
  const float* sun    = (const float*)d_in[1];
  const int*   ei     = (const int*)d_in[2];
  const int*   masks  = (const int*)d_in[3];
  const float* Wp     = (const float*)d_in[4];
  const float* bp     = (const float*)d_in[5];
  const float* Wself  = (const float*)d_in[6];
  const float* Wneigh = (const float*)d_in[7];
  const float* bconv  = (const float*)d_in[8];
  const float* lng    = (const float*)d_in[9];
  const float* lnb    = (const float*)d_in[10];
  const float* Wcod   = (const float*)d_in[11];
  const float* bcod   = (const float*)d_in[12];
  const float* a1W    = (const float*)d_in[13];
  const float* a1b    = (const float*)d_in[14];
  const float* a2W    = (const float*)d_in[15];
  const float* a2b    = (const float*)d_in[16];
  const float* oW     = (const float*)d_in[17];
  const float* ob     = (const float*)d_in[18];
  const float* fW1    = (const float*)d_in[19];
  const float* fb1    = (const float*)d_in[20];
  const float* fW2    = (const float*)d_in[21];
  const float* fb2    = (const float*)d_in[22];

  int B = in_sizes[0] / (NN*IN_DIM);
  int E = in_sizes[2] / 2;

  int*    adj_off = (int*)d_ws;
  int*    adj_src = adj_off + (NN+1);
  float*  dinv    = (float*)(adj_src + MAX_E);
  ushort* wb      = (ushort*)((char*)d_ws + 2576);

  setup_k<<<1, 256, 0, stream>>>(ei, E, Wp, Wself, Wneigh, a1W, adj_off, adj_src, dinv, wb);
  gnn_fused<<<B, 256, 0, stream>>>(nf, sun, masks, bp, bconv, lng, lnb, Wcod, bcod,
      a1b, a2W, a2b, oW, ob, fW1, fb1, fW2, fb2,
      adj_off, adj_src, dinv, wb, E, (float*)d_out);
}

// Round 5
// 1282.004 us; speedup vs baseline: 1.7923x; 1.0576x over previous
//
#include <hip/hip_runtime.h>

#define NN 64
#define HIDD 64
#define IN_DIM 34
#define SUN 70
#define NL 3
#define NH 5

typedef __attribute__((ext_vector_type(8))) short short8;
typedef __attribute__((ext_vector_type(4))) short short4v;
typedef __attribute__((ext_vector_type(4))) float f32x4;
typedef __attribute__((ext_vector_type(4))) unsigned u32x4;
#define MFMA16 __builtin_amdgcn_mfma_f32_16x16x32_bf16

__device__ __forceinline__ float sigm(float x){ return 1.0f/(1.0f+__expf(-x)); }
__device__ __forceinline__ float ftanh(float x){
  x = fminf(fmaxf(x, -15.0f), 15.0f);
  float e = __expf(2.0f*x);
  return (e-1.0f)/(e+1.0f);
}
__device__ __forceinline__ ushort f2bf(float f){
  union { float f; unsigned u; } v; v.f = f;
  unsigned r = v.u + 0x7fff + ((v.u >> 16) & 1);   // RNE
  return (ushort)(r >> 16);
}
__device__ __forceinline__ float bf2f(ushort h){
  union { unsigned u; float f; } v; v.u = ((unsigned)h) << 16;
  return v.f;
}
// swizzled offset within a [64][64] ushort plane
__device__ __forceinline__ int SWZ(int row, int col){
  return row*64 + (col ^ ((row&7)<<3));
}

// ws ushort offsets
#define O_WPH 0
#define O_WPL 4096
#define O_WSH 8192
#define O_WSL 20480
#define O_WNH 32768
#define O_WNL 45056
#define O_A1H 57344
#define O_A1L 67584
#define O_ADJH 77824
#define O_ADJL 81920

// Setup: dense normalized adjacency + weight bf16 hi/lo transpose conversion.
__global__ void setup_k(const int* __restrict__ ei, int E,
                        const float* __restrict__ Wp, const float* __restrict__ Wself,
                        const float* __restrict__ Wneigh, const float* __restrict__ a1W,
                        ushort* __restrict__ wb){
  __shared__ float A[64*64];
  __shared__ float dv[64];
  int tid = threadIdx.x;
  for (int i=tid;i<4096;i+=256) A[i]=0.0f;
  __syncthreads();
  if (tid==0){
    for (int e=0;e<E;++e) A[ei[E+e]*64 + ei[e]] += 1.0f;
  }
  __syncthreads();
  if (tid<64){
    float s=0.0f;
    for (int k=0;k<64;++k) s += A[tid*64+k];
    dv[tid] = 1.0f/fmaxf(s,1.0f);
  }
  __syncthreads();
  // adjacency hi/lo, row-major [dest][src]
  for (int i=tid;i<4096;i+=256){
    int d=i>>6;
    float v = A[i]*dv[d];
    ushort h=f2bf(v);
    wb[O_ADJH+i]=h; wb[O_ADJL+i]=f2bf(v-bf2f(h));
  }
  // WpT hi/lo: [n][k], k>=IN_DIM zero
  for (int i = tid; i < 4096; i += 256){
    int n = i>>6, k = i&63;
    float w = (k < IN_DIM) ? Wp[k*64 + n] : 0.0f;
    ushort h = f2bf(w);
    wb[O_WPH+i] = h;
    wb[O_WPL+i] = f2bf(w - bf2f(h));
  }
  // WsT/WnT hi/lo: [L][n][k]
  for (int i = tid; i < 3*4096; i += 256){
    int L = i>>12, r = i&4095, n = r>>6, k = r&63;
    float w = Wself[L*4096 + k*64 + n];
    ushort h = f2bf(w);
    wb[O_WSH+i] = h; wb[O_WSL+i] = f2bf(w - bf2f(h));
    w = Wneigh[L*4096 + k*64 + n];
    h = f2bf(w);
    wb[O_WNH+i] = h; wb[O_WNL+i] = f2bf(w - bf2f(h));
  }
  // A1T hi/lo: [hd][c][k]
  for (int i = tid; i < 5*2048; i += 256){
    int hd = i>>11, r = i&2047, cc = r>>6, k = r&63;
    float w = a1W[hd*2048 + k*32 + cc];
    ushort h = f2bf(w);
    wb[O_A1H+i] = h; wb[O_A1L+i] = f2bf(w - bf2f(h));
  }
}

__global__ __launch_bounds__(256, 4) void gnn_fused(
    const float* __restrict__ nf, const float* __restrict__ sun,
    const int* __restrict__ masks,
    const float* __restrict__ bp, const float* __restrict__ bconv,
    const float* __restrict__ lng, const float* __restrict__ lnb,
    const float* __restrict__ Wcod, const float* __restrict__ bcod,
    const float* __restrict__ a1b, const float* __restrict__ a2W,
    const float* __restrict__ a2b,
    const float* __restrict__ oW, const float* __restrict__ ob,
    const float* __restrict__ fW1, const float* __restrict__ fb1,
    const float* __restrict__ fW2, const float* __restrict__ fb2,
    const ushort* __restrict__ wb,
    float* __restrict__ out)
{
  __shared__ ushort s_xb[2*4096];  // x bf16 hi/lo, row-major swizzled
  __shared__ ushort s_nb[2*4096];  // nf staging -> yT -> xT (all swizzled planes)
  __shared__ float  s_scores[8];
  __shared__ float  s_mask[NH*64];
  __shared__ float  s_scH[NH*64];
  __shared__ unsigned s_wg[NH*68]; // packed wgt (hi | lo<<16), stride 68

  const int tid  = threadIdx.x;
  const int lane = tid & 63;
  const int wv   = __builtin_amdgcn_readfirstlane(tid >> 6);
  const int c    = lane & 15;
  const int hk   = lane >> 4;
  const long b   = blockIdx.x;
  const int arow = 16*wv + c;

  // ---- stage nf (hi/lo, swizzled) + masks ----
  for (int i = tid; i < NH*64; i += 256) s_mask[i] = (float)masks[i];
  for (int i = tid; i < NN*IN_DIM; i += 256){
    int n = i / IN_DIM, k = i - n*IN_DIM;
    float v = nf[b*(long)(NN*IN_DIM) + i];
    ushort h = f2bf(v);
    int o = SWZ(n,k);
    s_nb[o] = h; s_nb[4096+o] = f2bf(v - bf2f(h));
  }
  for (int i = tid; i < NN*(64-IN_DIM); i += 256){
    int n = i / (64-IN_DIM), k = IN_DIM + (i - n*(64-IN_DIM));
    int o = SWZ(n,k);
    s_nb[o] = 0; s_nb[4096+o] = 0;
  }
  __syncthreads();

  float xr[4][4];   // x C-frag: [nt][r], col=16nt+c, row=16wv+hk*4+r

  // ---- proj: x = relu(nf @ Wp + bp) ----
  {
    f32x4 acc[4];
    #pragma unroll
    for (int nt=0;nt<4;++nt){
      float bias = bp[16*nt + c];
      acc[nt] = (f32x4){bias,bias,bias,bias};
    }
    #pragma unroll
    for (int ks=0; ks<2; ++ks){
      int ao = SWZ(arow, hk*8 + ks*32);
      short8 aH = *(const short8*)&s_nb[ao];
      short8 aL = *(const short8*)&s_nb[4096+ao];
      #pragma unroll
      for (int nt=0;nt<4;++nt){
        int boff = (16*nt+c)*64 + hk*8 + ks*32;
        acc[nt] = MFMA16(aH, *(const short8*)(wb+O_WPH+boff), acc[nt], 0,0,0);
        acc[nt] = MFMA16(aH, *(const short8*)(wb+O_WPL+boff), acc[nt], 0,0,0);
        acc[nt] = MFMA16(aL, *(const short8*)(wb+O_WPH+boff), acc[nt], 0,0,0);
      }
    }
    #pragma unroll
    for (int nt=0;nt<4;++nt)
      #pragma unroll
      for (int r=0;r<4;++r){
        float v = fmaxf(acc[nt][r], 0.0f);
        xr[nt][r] = v;
        int row = 16*wv + hk*4 + r;
        int o = SWZ(row, 16*nt+c);
        ushort h = f2bf(v);
        s_xb[o] = h; s_xb[4096+o] = f2bf(v - bf2f(h));
      }
  }
  __syncthreads();

  // ---- GNN layers: h = x@Ws + A@(x@Wn) + bconv; x += relu(LN(h)) ----
  for (int L=0; L<NL; ++L){
    int a0 = SWZ(arow, hk*8), a1 = SWZ(arow, hk*8+32);
    short8 xA0H = *(const short8*)&s_xb[a0];
    short8 xA0L = *(const short8*)&s_xb[4096+a0];
    short8 xA1H = *(const short8*)&s_xb[a1];
    short8 xA1L = *(const short8*)&s_xb[4096+a1];

    const ushort* WsH = wb + O_WSH + L*4096;
    const ushort* WsL = wb + O_WSL + L*4096;
    const ushort* WnH = wb + O_WNH + L*4096;
    const ushort* WnL = wb + O_WNL + L*4096;

    // y = x @ Wn
    f32x4 y[4];
    #pragma unroll
    for (int nt=0;nt<4;++nt) y[nt] = (f32x4){0.f,0.f,0.f,0.f};
    #pragma unroll
    for (int nt=0;nt<4;++nt){
      int boff = (16*nt+c)*64 + hk*8;
      y[nt] = MFMA16(xA0H, *(const short8*)(WnH+boff   ), y[nt], 0,0,0);
      y[nt] = MFMA16(xA0H, *(const short8*)(WnL+boff   ), y[nt], 0,0,0);
      y[nt] = MFMA16(xA0L, *(const short8*)(WnH+boff   ), y[nt], 0,0,0);
      y[nt] = MFMA16(xA1H, *(const short8*)(WnH+boff+32), y[nt], 0,0,0);
      y[nt] = MFMA16(xA1H, *(const short8*)(WnL+boff+32), y[nt], 0,0,0);
      y[nt] = MFMA16(xA1L, *(const short8*)(WnH+boff+32), y[nt], 0,0,0);
    }
    // write yT (hi/lo, swizzled): yT[feat j][node]
    #pragma unroll
    for (int nt=0;nt<4;++nt){
      int j = 16*nt + c;
      int base = j*64 + ((16*wv + hk*4) ^ ((j&7)<<3));
      short4v vh, vl;
      #pragma unroll
      for (int r=0;r<4;++r){
        ushort h = f2bf(y[nt][r]);
        vh[r] = (short)h;
        vl[r] = (short)f2bf(y[nt][r] - bf2f(h));
      }
      *(short4v*)&s_nb[base]      = vh;
      *(short4v*)&s_nb[4096+base] = vl;
    }
    // h = bconv + x@Ws
    f32x4 acc[4];
    #pragma unroll
    for (int nt=0;nt<4;++nt){
      float bias = bconv[L*64 + 16*nt + c];
      acc[nt] = (f32x4){bias,bias,bias,bias};
    }
    #pragma unroll
    for (int nt=0;nt<4;++nt){
      int boff = (16*nt+c)*64 + hk*8;
      acc[nt] = MFMA16(xA0H, *(const short8*)(WsH+boff   ), acc[nt], 0,0,0);
      acc[nt] = MFMA16(xA0H, *(const short8*)(WsL+boff   ), acc[nt], 0,0,0);
      acc[nt] = MFMA16(xA0L, *(const short8*)(WsH+boff   ), acc[nt], 0,0,0);
      acc[nt] = MFMA16(xA1H, *(const short8*)(WsH+boff+32), acc[nt], 0,0,0);
      acc[nt] = MFMA16(xA1H, *(const short8*)(WsL+boff+32), acc[nt], 0,0,0);
      acc[nt] = MFMA16(xA1L, *(const short8*)(WsH+boff+32), acc[nt], 0,0,0);
    }
    __syncthreads();   // yT visible
    // h += A @ y
    {
      short8 adjH0 = *(const short8*)(wb + O_ADJH + arow*64 + hk*8);
      short8 adjL0 = *(const short8*)(wb + O_ADJL + arow*64 + hk*8);
      short8 adjH1 = *(const short8*)(wb + O_ADJH + arow*64 + hk*8 + 32);
      short8 adjL1 = *(const short8*)(wb + O_ADJL + arow*64 + hk*8 + 32);
      #pragma unroll
      for (int nt=0;nt<4;++nt){
        int j = 16*nt + c;
        int b0 = j*64 + ((hk*8     ) ^ ((j&7)<<3));
        int b1 = j*64 + ((hk*8 + 32) ^ ((j&7)<<3));
        short8 yH0 = *(const short8*)&s_nb[b0];
        short8 yL0 = *(const short8*)&s_nb[4096+b0];
        short8 yH1 = *(const short8*)&s_nb[b1];
        short8 yL1 = *(const short8*)&s_nb[4096+b1];
        acc[nt] = MFMA16(adjH0, yH0, acc[nt], 0,0,0);
        acc[nt] = MFMA16(adjH0, yL0, acc[nt], 0,0,0);
        acc[nt] = MFMA16(adjL0, yH0, acc[nt], 0,0,0);
        acc[nt] = MFMA16(adjH1, yH1, acc[nt], 0,0,0);
        acc[nt] = MFMA16(adjH1, yL1, acc[nt], 0,0,0);
        acc[nt] = MFMA16(adjL1, yH1, acc[nt], 0,0,0);
      }
    }
    // LN + relu + residual
    float g4[4], b4[4];
    #pragma unroll
    for (int nt=0;nt<4;++nt){ g4[nt]=lng[L*64+16*nt+c]; b4[nt]=lnb[L*64+16*nt+c]; }
    #pragma unroll
    for (int r=0;r<4;++r){
      float sm = acc[0][r]+acc[1][r]+acc[2][r]+acc[3][r];
      float sq = acc[0][r]*acc[0][r]+acc[1][r]*acc[1][r]+acc[2][r]*acc[2][r]+acc[3][r]*acc[3][r];
      #pragma unroll
      for (int d=1; d<16; d<<=1){ sm += __shfl_xor(sm, d, 64); sq += __shfl_xor(sq, d, 64); }
      float mu  = sm*(1.0f/64.0f);
      float var = sq*(1.0f/64.0f) - mu*mu;
      float rs  = rsqrtf(var + 1e-5f);
      int row = 16*wv + hk*4 + r;
      #pragma unroll
      for (int nt=0;nt<4;++nt){
        float hn = (acc[nt][r]-mu)*rs*g4[nt] + b4[nt];
        float v  = xr[nt][r] + fmaxf(hn, 0.0f);
        xr[nt][r] = v;
        int o = SWZ(row, 16*nt+c);
        ushort h = f2bf(v);
        s_xb[o] = h; s_xb[4096+o] = f2bf(v - bf2f(h));
      }
    }
    __syncthreads();
  }

  // ---- codons from registers ----
  {
    float wc[4];
    #pragma unroll
    for (int nt=0;nt<4;++nt) wc[nt] = Wcod[16*nt+c];
    #pragma unroll
    for (int r=0;r<4;++r){
      float p = xr[0][r]*wc[0] + xr[1][r]*wc[1] + xr[2][r]*wc[2] + xr[3][r]*wc[3];
      #pragma unroll
      for (int d=1; d<16; d<<=1) p += __shfl_xor(p, d, 64);
      if (c == 0){
        int row = 16*wv + hk*4 + r;
        out[b*69 + row] = sigm(p + bcod[0]);
      }
    }
  }

  // ---- write xT (pool B-operand) into s_nb from registers ----
  #pragma unroll
  for (int nt=0;nt<4;++nt){
    int j = 16*nt + c;
    int base = j*64 + ((16*wv + hk*4) ^ ((j&7)<<3));
    short4v vh, vl;
    #pragma unroll
    for (int r=0;r<4;++r){
      ushort h = f2bf(xr[nt][r]);
      vh[r] = (short)h;
      vl[r] = (short)f2bf(xr[nt][r] - bf2f(h));
    }
    *(short4v*)&s_nb[base]      = vh;
    *(short4v*)&s_nb[4096+base] = vl;
  }

  // ---- heads phase 1: masked scores -> s_scH ----
  {
    int a0 = SWZ(arow, hk*8), a1 = SWZ(arow, hk*8+32);
    short8 xA0H = *(const short8*)&s_xb[a0];
    short8 xA0L = *(const short8*)&s_xb[4096+a0];
    short8 xA1H = *(const short8*)&s_xb[a1];
    short8 xA1L = *(const short8*)&s_xb[4096+a1];
    #pragma unroll
    for (int hd=0; hd<NH; ++hd){
      f32x4 acc2[2];
      acc2[0] = (f32x4){0.f,0.f,0.f,0.f};
      acc2[1] = (f32x4){0.f,0.f,0.f,0.f};
      #pragma unroll
      for (int nt=0;nt<2;++nt){
        int boff = hd*2048 + (16*nt+c)*64 + hk*8;
        acc2[nt] = MFMA16(xA0H, *(const short8*)(wb+O_A1H+boff   ), acc2[nt], 0,0,0);
        acc2[nt] = MFMA16(xA0H, *(const short8*)(wb+O_A1L+boff   ), acc2[nt], 0,0,0);
        acc2[nt] = MFMA16(xA0L, *(const short8*)(wb+O_A1H+boff   ), acc2[nt], 0,0,0);
        acc2[nt] = MFMA16(xA1H, *(const short8*)(wb+O_A1H+boff+32), acc2[nt], 0,0,0);
        acc2[nt] = MFMA16(xA1H, *(const short8*)(wb+O_A1L+boff+32), acc2[nt], 0,0,0);
        acc2[nt] = MFMA16(xA1L, *(const short8*)(wb+O_A1H+boff+32), acc2[nt], 0,0,0);
      }
      float b1v0 = a1b[hd*32 +      c];
      float b1v1 = a1b[hd*32 + 16 + c];
      float a2v0 = a2W[hd*32 +      c];
      float a2v1 = a2W[hd*32 + 16 + c];
      #pragma unroll
      for (int r=0;r<4;++r){
        int row = 16*wv + hk*4 + r;
        float m = s_mask[hd*64 + row];
        float sp = ftanh(fmaf(m, acc2[0][r], b1v0)) * a2v0
                 + ftanh(fmaf(m, acc2[1][r], b1v1)) * a2v1;
        #pragma unroll
        for (int d=1; d<16; d<<=1) sp += __shfl_xor(sp, d, 64);
        if (c==0) s_scH[hd*64 + row] = sp + a2b[hd] + (1.0f - m)*(-1.0e9f);
      }
    }
  }
  __syncthreads();

  // ---- softmax -> packed bf16 hi/lo weights ----
  #pragma unroll
  for (int hd=0; hd<NH; ++hd){
    float sv = s_scH[hd*64 + lane];
    float mx = sv;
    #pragma unroll
    for (int d=32; d>=1; d>>=1) mx = fmaxf(mx, __shfl_xor(mx, d, 64));
    float e = __expf(sv - mx);
    float ssum = e;
    #pragma unroll
    for (int d=32; d>=1; d>>=1) ssum += __shfl_xor(ssum, d, 64);
    float wgt = (e / ssum) * s_mask[hd*64 + lane];
    ushort h = f2bf(wgt);
    ushort l = f2bf(wgt - bf2f(h));
    s_wg[hd*68 + lane] = (unsigned)h | ((unsigned)l << 16);
  }
  __syncthreads();

  // ---- pool via MFMA + output dots (wave 0 only) ----
  if (wv == 0){
    f32x4 pacc[4];
    #pragma unroll
    for (int nt=0;nt<4;++nt) pacc[nt] = (f32x4){0.f,0.f,0.f,0.f};
    #pragma unroll
    for (int ks=0; ks<2; ++ks){
      short8 wH = (short8){0,0,0,0,0,0,0,0};
      short8 wL = (short8){0,0,0,0,0,0,0,0};
      if (c < 5){
        u32x4 w0 = *(const u32x4*)&s_wg[c*68 + hk*8 + ks*32];
        u32x4 w1 = *(const u32x4*)&s_wg[c*68 + hk*8 + ks*32 + 4];
        #pragma unroll
        for (int i=0;i<4;++i){
          wH[i]   = (short)(w0[i] & 0xffffu);
          wL[i]   = (short)(w0[i] >> 16);
          wH[4+i] = (short)(w1[i] & 0xffffu);
          wL[4+i] = (short)(w1[i] >> 16);
        }
      }
      #pragma unroll
      for (int nt=0;nt<4;++nt){
        int j = 16*nt + c;
        int bo = j*64 + ((hk*8 + ks*32) ^ ((j&7)<<3));
        short8 xH = *(const short8*)&s_nb[bo];
        short8 xL = *(const short8*)&s_nb[4096+bo];
        pacc[nt] = MFMA16(wH, xH, pacc[nt], 0,0,0);
        pacc[nt] = MFMA16(wH, xL, pacc[nt], 0,0,0);
        pacc[nt] = MFMA16(wL, xH, pacc[nt], 0,0,0);
      }
    }
    #pragma unroll
    for (int r=0;r<4;++r){
      int hd  = hk*4 + r;
      int hds = (hd < 5) ? hd : 4;
      float dot = 0.0f;
      #pragma unroll
      for (int nt=0;nt<4;++nt) dot = fmaf(pacc[nt][r], oW[hds*64 + 16*nt + c], dot);
      #pragma unroll
      for (int d=1; d<16; d<<=1) dot += __shfl_xor(dot, d, 64);
      if (c==0 && hd<5) s_scores[hd] = sigm(dot + ob[hd]);
    }
  }
  __syncthreads();

  // ---- FiLM + scalar outputs ----
  if (wv < 2 && lane < 32){
    int idx = wv;
    float t = fb1[idx*32 + lane];
    for (int k=0;k<SUN;++k) t = fmaf(sun[b*(long)SUN + k], fW1[idx*SUN*32 + k*32 + lane], t);
    t = fmaxf(t, 0.0f);
    float g  = t * fW2[idx*64 + lane*2 + 0];
    float be = t * fW2[idx*64 + lane*2 + 1];
    #pragma unroll
    for (int d=16; d>=1; d>>=1){ g += __shfl_xor(g, d, 64); be += __shfl_xor(be, d, 64); }
    if (lane==0){
      g  += fb2[idx*2 + 0];
      be += fb2[idx*2 + 1];
      float base = s_scores[3+idx];
      out[b*69 + 67 + idx] = sigm(fmaf(g, base, be));
    }
  }
  if (tid < 3) out[b*69 + 64 + tid] = s_scores[tid];
}

extern "C" void kernel_launch(void* const* d_in, const int* in_sizes, int n_in,
                              void* d_out, int out_size, void* d_ws, size_t ws_size,
                              hipStream_t stream){
  const float* nf     = (const float*)d_in[0];
  const float* sun    = (const float*)d_in[1];
  const int*   ei     = (const int*)d_in[2];
  const int*   masks  = (const int*)d_in[3];
  const float* Wp     = (const float*)d_in[4];
  const float* bp     = (const float*)d_in[5];
  const float* Wself  = (const float*)d_in[6];
  const float* Wneigh = (const float*)d_in[7];
  const float* bconv  = (const float*)d_in[8];
  const float* lng    = (const float*)d_in[9];
  const float* lnb    = (const float*)d_in[10];
  const float* Wcod   = (const float*)d_in[11];
  const float* bcod   = (const float*)d_in[12];
  const float* a1W    = (const float*)d_in[13];
  const float* a1b    = (const float*)d_in[14];
  const float* a2W    = (const float*)d_in[15];
  const float* a2b    = (const float*)d_in[16];
  const float* oW     = (const float*)d_in[17];
  const float* ob     = (const float*)d_in[18];
  const float* fW1    = (const float*)d_in[19];
  const float* fb1    = (const float*)d_in[20];
  const float* fW2    = (const float*)d_in[21];
  const float* fb2    = (const float*)d_in[22];

  int B = in_sizes[0] / (NN*IN_DIM);
  int E = in_sizes[2] / 2;

  ushort* wbuf = (ushort*)d_ws;

  setup_k<<<1, 256, 0, stream>>>(ei, E, Wp, Wself, Wneigh, a1W, wbuf);
  gnn_fused<<<B, 256, 0, stream>>>(nf, sun, masks, bp, bconv, lng, lnb, Wcod, bcod,
      a1b, a2W, a2b, oW, ob, fW1, fb1, fW2, fb2, wbuf, (float*)d_out);
}

// Round 6
// 1045.138 us; speedup vs baseline: 2.1985x; 1.2266x over previous
//
#include <hip/hip_runtime.h>

#define NN 64
#define IN_DIM 34
#define SUN 70
#define NL 3
#define NH 5

typedef __attribute__((ext_vector_type(8))) short short8;
typedef __attribute__((ext_vector_type(4))) short short4v;
typedef __attribute__((ext_vector_type(4))) float f32x4;
#define MFMA16 __builtin_amdgcn_mfma_f32_16x16x32_bf16

__device__ __forceinline__ float sigm(float x){ return 1.0f/(1.0f+__expf(-x)); }
__device__ __forceinline__ float ftanh(float x){
  x = fminf(fmaxf(x, -15.0f), 15.0f);
  float e = __expf(2.0f*x);
  return (e-1.0f)/(e+1.0f);
}
__device__ __forceinline__ ushort f2bf(float f){
  union { float f; unsigned u; } v; v.f = f;
  unsigned r = v.u + 0x7fff + ((v.u >> 16) & 1);   // RNE
  return (ushort)(r >> 16);
}
__device__ __forceinline__ float bf2f(ushort h){
  union { unsigned u; float f; } v; v.u = ((unsigned)h) << 16;
  return v.f;
}

// ws ushort offsets
#define O_WPH 0
#define O_WPL 4096
#define O_WSH 8192
#define O_WSL 20480
#define O_WNH 32768
#define O_WNL 45056
#define O_A1H 57344
#define O_A1L 67584
#define O_ADJH 77824
#define O_ADJL 81920

// LDS frag read: storage [entity][k] swizzled; row = 16t+c, k = hk*8 + kt*32
#define LDF(plane, t, kt) \
  (*(const short8*)&(plane)[(16*(t)+c)*64 + (((hk*8)+(kt)*32) ^ (((16*(t)+c)&7)<<3))])
// global wb frag read (linear layout)
#define GBF(base, t, kt) \
  (*(const short8*)&(base)[(16*(t)+c)*64 + hk*8 + (kt)*32])

// Setup: dense normalized adjacency + weight bf16 hi/lo transpose conversion.
__global__ void setup_k(const int* __restrict__ ei, int E,
                        const float* __restrict__ Wp, const float* __restrict__ Wself,
                        const float* __restrict__ Wneigh, const float* __restrict__ a1W,
                        ushort* __restrict__ wb){
  __shared__ float A[64*64];
  __shared__ float dv[64];
  int tid = threadIdx.x;
  for (int i=tid;i<4096;i+=256) A[i]=0.0f;
  __syncthreads();
  if (tid==0){
    for (int e=0;e<E;++e) A[ei[E+e]*64 + ei[e]] += 1.0f;
  }
  __syncthreads();
  if (tid<64){
    float s=0.0f;
    for (int k=0;k<64;++k) s += A[tid*64+k];
    dv[tid] = 1.0f/fmaxf(s,1.0f);
  }
  __syncthreads();
  // adjacency hi/lo, row-major [dest][src]
  for (int i=tid;i<4096;i+=256){
    int d=i>>6;
    float v = A[i]*dv[d];
    ushort h=f2bf(v);
    wb[O_ADJH+i]=h; wb[O_ADJL+i]=f2bf(v-bf2f(h));
  }
  // WpT hi/lo: [outfeat][infeat], k>=IN_DIM zero
  for (int i = tid; i < 4096; i += 256){
    int n = i>>6, k = i&63;
    float w = (k < IN_DIM) ? Wp[k*64 + n] : 0.0f;
    ushort h = f2bf(w);
    wb[O_WPH+i] = h;
    wb[O_WPL+i] = f2bf(w - bf2f(h));
  }
  // WsT/WnT hi/lo: [L][outfeat][infeat]
  for (int i = tid; i < 3*4096; i += 256){
    int L = i>>12, r = i&4095, n = r>>6, k = r&63;
    float w = Wself[L*4096 + k*64 + n];
    ushort h = f2bf(w);
    wb[O_WSH+i] = h; wb[O_WSL+i] = f2bf(w - bf2f(h));
    w = Wneigh[L*4096 + k*64 + n];
    h = f2bf(w);
    wb[O_WNH+i] = h; wb[O_WNL+i] = f2bf(w - bf2f(h));
  }
  // A1T hi/lo: [hd][a1col][infeat]
  for (int i = tid; i < 5*2048; i += 256){
    int hd = i>>11, r = i&2047, cc = r>>6, k = r&63;
    float w = a1W[hd*2048 + k*32 + cc];
    ushort h = f2bf(w);
    wb[O_A1H+i] = h; wb[O_A1L+i] = f2bf(w - bf2f(h));
  }
}

__global__ __launch_bounds__(256, 1) void gnn_fused(
    const float* __restrict__ nf, const float* __restrict__ sun,
    const int* __restrict__ masks,
    const float* __restrict__ bp, const float* __restrict__ bconv,
    const float* __restrict__ lng, const float* __restrict__ lnb,
    const float* __restrict__ Wcod, const float* __restrict__ bcod,
    const float* __restrict__ a1b, const float* __restrict__ a2W,
    const float* __restrict__ a2b,
    const float* __restrict__ oW, const float* __restrict__ ob,
    const float* __restrict__ fW1, const float* __restrict__ fb1,
    const float* __restrict__ fW2, const float* __restrict__ fb2,
    const ushort* __restrict__ wb, int B,
    float* __restrict__ out)
{
  __shared__ ushort s_x[4][8192];   // per-wave x: hi [0,4096), lo [4096,8192), [node][feat] swizzled
  __shared__ ushort s_n[4][8192];   // per-wave scratch: nf staging -> yT [outfeat][node]

  const int tid  = threadIdx.x;
  const int lane = tid & 63;
  const int wv   = tid >> 6;
  const int c    = lane & 15;
  const int hk   = lane >> 4;
  const long e   = (long)blockIdx.x*4 + wv;
  if (e >= B) return;

  ushort* xp = s_x[wv];
  ushort* np = s_n[wv];
  float*  oute = out + e*69;

  // ---- stage nf: lane = node, pack 4 feats per b64 write (hi/lo), zero-pad to 64 ----
  {
    const float* nfe = nf + e*(long)(NN*IN_DIM);
    int n = lane;
    int key = (n&7)<<3;
    #pragma unroll
    for (int k4 = 0; k4 < 9; ++k4){
      short4v vh, vl;
      #pragma unroll
      for (int q=0;q<4;++q){
        int k = k4*4+q;
        float v = (k < IN_DIM) ? nfe[n*IN_DIM + k] : 0.0f;
        ushort h = f2bf(v);
        vh[q] = (short)h; vl[q] = (short)f2bf(v - bf2f(h));
      }
      int off = n*64 + ((k4*4) ^ key);
      *(short4v*)&np[off] = vh; *(short4v*)&np[4096+off] = vl;
    }
    #pragma unroll
    for (int k4 = 9; k4 < 16; ++k4){
      int off = n*64 + ((k4*4) ^ key);
      *(short4v*)&np[off]      = (short4v){0,0,0,0};
      *(short4v*)&np[4096+off] = (short4v){0,0,0,0};
    }
  }

  float xr[4][4][4];   // x, orientation: [mt=feat-tile][nt=node-tile][r]; col=16nt+c (node), row=16mt+hk*4+r (feat)

  // ---- proj^T = Wp^T(A) @ nf^T(B): col=node, row=outfeat ----
  {
    f32x4 acc[4][4];
    #pragma unroll
    for (int mt=0;mt<4;++mt){
      f32x4 b4 = *(const f32x4*)&bp[16*mt + hk*4];
      #pragma unroll
      for (int nt=0;nt<4;++nt) acc[mt][nt] = b4;
    }
    #pragma unroll
    for (int kt=0; kt<2; ++kt){
      short8 bH[4], bL[4];
      #pragma unroll
      for (int t=0;t<4;++t){ bH[t]=LDF(np,t,kt); bL[t]=LDF(np+4096,t,kt); }
      #pragma unroll
      for (int mt=0;mt<4;++mt){
        short8 aH = GBF(wb+O_WPH, mt, kt);
        short8 aL = GBF(wb+O_WPL, mt, kt);
        #pragma unroll
        for (int nt=0;nt<4;++nt){
          acc[mt][nt] = MFMA16(aH, bH[nt], acc[mt][nt], 0,0,0);
          acc[mt][nt] = MFMA16(aH, bL[nt], acc[mt][nt], 0,0,0);
          acc[mt][nt] = MFMA16(aL, bH[nt], acc[mt][nt], 0,0,0);
        }
      }
    }
    #pragma unroll
    for (int mt=0;mt<4;++mt)
      #pragma unroll
      for (int nt=0;nt<4;++nt){
        int node = 16*nt + c;
        short4v vh, vl;
        #pragma unroll
        for (int r=0;r<4;++r){
          float v = fmaxf(acc[mt][nt][r], 0.0f);
          xr[mt][nt][r] = v;
          ushort h = f2bf(v);
          vh[r] = (short)h; vl[r] = (short)f2bf(v - bf2f(h));
        }
        int off = node*64 + ((16*mt + hk*4) ^ ((node&7)<<3));
        *(short4v*)&xp[off] = vh; *(short4v*)&xp[4096+off] = vl;
      }
  }

  // ---- GNN layers ----
  #pragma unroll 1
  for (int L=0; L<NL; ++L){
    const ushort* WsH = wb + O_WSH + L*4096;
    const ushort* WsL = wb + O_WSL + L*4096;
    const ushort* WnH = wb + O_WNH + L*4096;
    const ushort* WnL = wb + O_WNL + L*4096;

    // cache x frags (serve as A in y-step and B in h-step)
    short8 xH[4][2], xL[4][2];
    #pragma unroll
    for (int t=0;t<4;++t)
      #pragma unroll
      for (int kt=0;kt<2;++kt){ xH[t][kt]=LDF(xp,t,kt); xL[t][kt]=LDF(xp+4096,t,kt); }

    // y = x(A) @ Wn(B): col=outfeat, row=node
    f32x4 y[4][4];
    #pragma unroll
    for (int mt=0;mt<4;++mt)
      #pragma unroll
      for (int nt=0;nt<4;++nt) y[mt][nt] = (f32x4){0.f,0.f,0.f,0.f};
    #pragma unroll
    for (int kt=0;kt<2;++kt)
      #pragma unroll
      for (int nt=0;nt<4;++nt){
        short8 wH = GBF(WnH, nt, kt);
        short8 wL = GBF(WnL, nt, kt);
        #pragma unroll
        for (int mt=0;mt<4;++mt){
          y[mt][nt] = MFMA16(xH[mt][kt], wH, y[mt][nt], 0,0,0);
          y[mt][nt] = MFMA16(xH[mt][kt], wL, y[mt][nt], 0,0,0);
          y[mt][nt] = MFMA16(xL[mt][kt], wH, y[mt][nt], 0,0,0);
        }
      }
    // write yT [outfeat][node] (b64, swizzled)
    #pragma unroll
    for (int nt=0;nt<4;++nt)
      #pragma unroll
      for (int mt=0;mt<4;++mt){
        int of = 16*nt + c;
        short4v vh, vl;
        #pragma unroll
        for (int r=0;r<4;++r){
          ushort h = f2bf(y[mt][nt][r]);
          vh[r] = (short)h; vl[r] = (short)f2bf(y[mt][nt][r] - bf2f(h));
        }
        int off = of*64 + ((16*mt + hk*4) ^ ((of&7)<<3));
        *(short4v*)&np[off] = vh; *(short4v*)&np[4096+off] = vl;
      }

    // h^T = Ws^T(A) @ x^T(B) + y^T(A) @ adjT(B) + bconv : col=node, row=outfeat
    f32x4 h[4][4];
    #pragma unroll
    for (int mt=0;mt<4;++mt){
      f32x4 b4 = *(const f32x4*)&bconv[L*64 + 16*mt + hk*4];
      #pragma unroll
      for (int nt=0;nt<4;++nt) h[mt][nt] = b4;
    }
    #pragma unroll
    for (int kt=0;kt<2;++kt)
      #pragma unroll
      for (int mt=0;mt<4;++mt){
        short8 aH = GBF(WsH, mt, kt);
        short8 aL = GBF(WsL, mt, kt);
        #pragma unroll
        for (int nt=0;nt<4;++nt){
          h[mt][nt] = MFMA16(aH, xH[nt][kt], h[mt][nt], 0,0,0);
          h[mt][nt] = MFMA16(aH, xL[nt][kt], h[mt][nt], 0,0,0);
          h[mt][nt] = MFMA16(aL, xH[nt][kt], h[mt][nt], 0,0,0);
        }
      }
    #pragma unroll
    for (int kt=0;kt<2;++kt){
      short8 bAH[4], bAL[4];
      #pragma unroll
      for (int nt=0;nt<4;++nt){ bAH[nt]=GBF(wb+O_ADJH, nt, kt); bAL[nt]=GBF(wb+O_ADJL, nt, kt); }
      #pragma unroll
      for (int mt=0;mt<4;++mt){
        short8 aH = LDF(np, mt, kt);        // yT hi
        short8 aL = LDF(np+4096, mt, kt);   // yT lo
        #pragma unroll
        for (int nt=0;nt<4;++nt){
          h[mt][nt] = MFMA16(aH, bAH[nt], h[mt][nt], 0,0,0);
          h[mt][nt] = MFMA16(aH, bAL[nt], h[mt][nt], 0,0,0);
          h[mt][nt] = MFMA16(aL, bAH[nt], h[mt][nt], 0,0,0);
        }
      }
    }

    // LN over feats (rows) per node (col) + relu + residual
    f32x4 g4[4], bb4[4];
    #pragma unroll
    for (int mt=0;mt<4;++mt){
      g4[mt]  = *(const f32x4*)&lng[L*64 + 16*mt + hk*4];
      bb4[mt] = *(const f32x4*)&lnb[L*64 + 16*mt + hk*4];
    }
    #pragma unroll
    for (int nt=0;nt<4;++nt){
      float sm=0.0f, sq=0.0f;
      #pragma unroll
      for (int mt=0;mt<4;++mt)
        #pragma unroll
        for (int r=0;r<4;++r){ float v=h[mt][nt][r]; sm+=v; sq+=v*v; }
      sm += __shfl_xor(sm,16,64); sm += __shfl_xor(sm,32,64);
      sq += __shfl_xor(sq,16,64); sq += __shfl_xor(sq,32,64);
      float mu  = sm*(1.0f/64.0f);
      float var = sq*(1.0f/64.0f) - mu*mu;
      float rs  = rsqrtf(var + 1e-5f);
      #pragma unroll
      for (int mt=0;mt<4;++mt)
        #pragma unroll
        for (int r=0;r<4;++r){
          float hn = (h[mt][nt][r]-mu)*rs*g4[mt][r] + bb4[mt][r];
          xr[mt][nt][r] += fmaxf(hn, 0.0f);
        }
    }
    // write x back [node][feat] (b64, swizzled)
    #pragma unroll
    for (int mt=0;mt<4;++mt)
      #pragma unroll
      for (int nt=0;nt<4;++nt){
        int node = 16*nt + c;
        short4v vh, vl;
        #pragma unroll
        for (int r=0;r<4;++r){
          float v = xr[mt][nt][r];
          ushort h2 = f2bf(v);
          vh[r] = (short)h2; vl[r] = (short)f2bf(v - bf2f(h2));
        }
        int off = node*64 + ((16*mt + hk*4) ^ ((node&7)<<3));
        *(short4v*)&xp[off] = vh; *(short4v*)&xp[4096+off] = vl;
      }
  }

  // ---- codons: sigmoid(x@Wcod + b) from registers ----
  {
    f32x4 wc4[4];
    #pragma unroll
    for (int mt=0;mt<4;++mt) wc4[mt] = *(const f32x4*)&Wcod[16*mt + hk*4];
    float bc = bcod[0];
    #pragma unroll
    for (int nt=0;nt<4;++nt){
      float p = 0.0f;
      #pragma unroll
      for (int mt=0;mt<4;++mt)
        #pragma unroll
        for (int r=0;r<4;++r) p = fmaf(xr[mt][nt][r], wc4[mt][r], p);
      p += __shfl_xor(p,16,64); p += __shfl_xor(p,32,64);
      if (hk==0) oute[16*nt + c] = sigm(p + bc);
    }
  }

  // ---- heads: scores^T = A1^T(A) @ x^T(B); softmax + pool + out-dot in registers ----
  float sc[NH];
  {
    short8 xH[4][2], xL[4][2];
    #pragma unroll
    for (int t=0;t<4;++t)
      #pragma unroll
      for (int kt=0;kt<2;++kt){ xH[t][kt]=LDF(xp,t,kt); xL[t][kt]=LDF(xp+4096,t,kt); }

    #pragma unroll 1
    for (int hd=0; hd<NH; ++hd){
      float m4[4];
      #pragma unroll
      for (int nt=0;nt<4;++nt) m4[nt] = (float)masks[hd*64 + 16*nt + c];

      f32x4 s2[2][4];
      #pragma unroll
      for (int mt=0;mt<2;++mt)
        #pragma unroll
        for (int nt=0;nt<4;++nt) s2[mt][nt] = (f32x4){0.f,0.f,0.f,0.f};
      const ushort* A1H = wb + O_A1H + hd*2048;
      const ushort* A1L = wb + O_A1L + hd*2048;
      #pragma unroll
      for (int kt=0;kt<2;++kt)
        #pragma unroll
        for (int mt=0;mt<2;++mt){
          short8 aH = GBF(A1H, mt, kt);
          short8 aL = GBF(A1L, mt, kt);
          #pragma unroll
          for (int nt=0;nt<4;++nt){
            s2[mt][nt] = MFMA16(aH, xH[nt][kt], s2[mt][nt], 0,0,0);
            s2[mt][nt] = MFMA16(aH, xL[nt][kt], s2[mt][nt], 0,0,0);
            s2[mt][nt] = MFMA16(aL, xH[nt][kt], s2[mt][nt], 0,0,0);
          }
        }
      // tanh(m*acc + b1) @ a2W, reduce over a1cols
      float sp[4] = {0.f,0.f,0.f,0.f};
      #pragma unroll
      for (int mt=0;mt<2;++mt){
        f32x4 b1v = *(const f32x4*)&a1b[hd*32 + 16*mt + hk*4];
        f32x4 a2v = *(const f32x4*)&a2W[hd*32 + 16*mt + hk*4];
        #pragma unroll
        for (int nt=0;nt<4;++nt)
          #pragma unroll
          for (int r=0;r<4;++r)
            sp[nt] = fmaf(ftanh(fmaf(m4[nt], s2[mt][nt][r], b1v[r])), a2v[r], sp[nt]);
      }
      float a2bv = a2b[hd];
      float sv[4];
      #pragma unroll
      for (int nt=0;nt<4;++nt){
        float t = sp[nt];
        t += __shfl_xor(t,16,64); t += __shfl_xor(t,32,64);
        sv[nt] = t + a2bv + (1.0f - m4[nt])*(-1.0e9f);
      }
      // softmax over 64 nodes (4 in-lane x 16 lanes)
      float mx = fmaxf(fmaxf(sv[0],sv[1]), fmaxf(sv[2],sv[3]));
      #pragma unroll
      for (int d=1; d<16; d<<=1) mx = fmaxf(mx, __shfl_xor(mx,d,64));
      float ee[4], ssum=0.0f;
      #pragma unroll
      for (int nt=0;nt<4;++nt){ ee[nt] = __expf(sv[nt]-mx); ssum += ee[nt]; }
      #pragma unroll
      for (int d=1; d<16; d<<=1) ssum += __shfl_xor(ssum,d,64);
      float inv = 1.0f/ssum;
      float wgt[4];
      #pragma unroll
      for (int nt=0;nt<4;++nt) wgt[nt] = ee[nt]*inv*m4[nt];
      // pooled[feat] = sum_node wgt*x  (in-lane over nt, shuffle over 16 col-lanes)
      float pool[4][4];
      #pragma unroll
      for (int mt=0;mt<4;++mt)
        #pragma unroll
        for (int r=0;r<4;++r){
          float p = wgt[0]*xr[mt][0][r] + wgt[1]*xr[mt][1][r]
                  + wgt[2]*xr[mt][2][r] + wgt[3]*xr[mt][3][r];
          #pragma unroll
          for (int d=1; d<16; d<<=1) p += __shfl_xor(p,d,64);
          pool[mt][r] = p;
        }
      // out dot
      float dt = 0.0f;
      #pragma unroll
      for (int mt=0;mt<4;++mt){
        f32x4 ow = *(const f32x4*)&oW[hd*64 + 16*mt + hk*4];
        #pragma unroll
        for (int r=0;r<4;++r) dt = fmaf(pool[mt][r], ow[r], dt);
      }
      dt += __shfl_xor(dt,16,64); dt += __shfl_xor(dt,32,64);
      sc[hd] = sigm(dt + ob[hd]);
    }
  }

  // ---- FiLM: lanes 0-31 idx0, 32-63 idx1 ----
  {
    int idx = lane >> 5;
    int j   = lane & 31;
    float t = fb1[idx*32 + j];
    const float* fw = fW1 + idx*SUN*32 + j;
    const float* se = sun + e*(long)SUN;
    #pragma unroll 2
    for (int k=0;k<SUN;++k) t = fmaf(se[k], fw[k*32], t);
    t = fmaxf(t, 0.0f);
    float g  = t * fW2[idx*64 + j*2 + 0];
    float be = t * fW2[idx*64 + j*2 + 1];
    #pragma unroll
    for (int d=1; d<32; d<<=1){ g += __shfl_xor(g,d,64); be += __shfl_xor(be,d,64); }
    float base = (lane < 32) ? sc[3] : sc[4];
    if (j == 0){
      g  += fb2[idx*2 + 0];
      be += fb2[idx*2 + 1];
      oute[67 + idx] = sigm(fmaf(g, base, be));
    }
  }
  if (lane == 0){
    oute[64] = sc[0];
    oute[65] = sc[1];
    oute[66] = sc[2];
  }
}

extern "C" void kernel_launch(void* const* d_in, const int* in_sizes, int n_in,
                              void* d_out, int out_size, void* d_ws, size_t ws_size,
                              hipStream_t stream){
  const float* nf     = (const float*)d_in[0];
  const float* sun    = (const float*)d_in[1];
  const int*   ei     = (const int*)d_in[2];
  const int*   masks  = (const int*)d_in[3];
  const float* Wp     = (const float*)d_in[4];
  const float* bp     = (const float*)d_in[5];
  const float* Wself  = (const float*)d_in[6];
  const float* Wneigh = (const float*)d_in[7];
  const float* bconv  = (const float*)d_in[8];
  const float* lng    = (const float*)d_in[9];
  const float* lnb    = (const float*)d_in[10];
  const float* Wcod   = (const float*)d_in[11];
  const float* bcod   = (const float*)d_in[12];
  const float* a1W    = (const float*)d_in[13];
  const float* a1b    = (const float*)d_in[14];
  const float* a2W    = (const float*)d_in[15];
  const float* a2b    = (const float*)d_in[16];
  const float* oW     = (const float*)d_in[17];
  const float* ob     = (const float*)d_in[18];
  const float* fW1    = (const float*)d_in[19];
  const float* fb1    = (const float*)d_in[20];
  const float* fW2    = (const float*)d_in[21];
  const float* fb2    = (const float*)d_in[22];

  int B = in_sizes[0] / (NN*IN_DIM);
  int E = in_sizes[2] / 2;

  ushort* wbuf = (ushort*)d_ws;

  setup_k<<<1, 256, 0, stream>>>(ei, E, Wp, Wself, Wneigh, a1W, wbuf);
  int nb = (B + 3) / 4;
  gnn_fused<<<nb, 256, 0, stream>>>(nf, sun, masks, bp, bconv, lng, lnb, Wcod, bcod,
      a1b, a2W, a2b, oW, ob, fW1, fb1, fW2, fb2, wbuf, B, (float*)d_out);
}